// Round 1
// baseline (412.824 us; speedup 1.0000x reference)
//
#include <hip/hip_runtime.h>

// Depth-to-space s=2: out[b, 2h+j, 2w+k, c] = in[b, h, w, 4c+2k+j]
// In:  (16, 128, 128, 256) fp32   Out: (16, 256, 256, 64) fp32
//
// One thread per (b,h,w,c), c = tid & 63.
//   - float4 load of input channels [4c, 4c+3]: flat float4 index == tid
//     (perfectly coalesced, 16 B/lane).
//   - 4 scalar stores; within a wave lanes span c=0..63 at fixed (b,h,w),
//     so each store instruction writes one contiguous 256 B run.

__global__ __launch_bounds__(256) void d2s_kernel(const float4* __restrict__ in4,
                                                  float* __restrict__ out) {
    const unsigned t = blockIdx.x * 256u + threadIdx.x;
    // t < 16*128*128*64 = 16,777,216 (grid sized exactly; no bounds check needed)

    const float4 v = in4[t];

    const unsigned c = t & 63u;          // output channel
    const unsigned w = (t >> 6) & 127u;  // input col
    const unsigned h = (t >> 13) & 127u; // input row
    const unsigned b = t >> 20;          // batch

    // out flat index: ((b*256 + 2h)*256 + 2w)*64 + c
    const unsigned base = b * 4194304u + h * 32768u + w * 128u + c;

    out[base]                 = v.x;  // (j=0,k=0)
    out[base + 64u]           = v.z;  // (j=0,k=1)
    out[base + 16384u]        = v.y;  // (j=1,k=0)
    out[base + 16384u + 64u]  = v.w;  // (j=1,k=1)
}

extern "C" void kernel_launch(void* const* d_in, const int* in_sizes, int n_in,
                              void* d_out, int out_size, void* d_ws, size_t ws_size,
                              hipStream_t stream) {
    const float4* in4 = (const float4*)d_in[0];
    float* out = (float*)d_out;

    const int n_threads = 16 * 128 * 128 * 64; // 16,777,216
    const int block = 256;
    const int grid = n_threads / block;        // 65,536

    d2s_kernel<<<grid, block, 0, stream>>>(in4, out);
}